// Round 12
// baseline (160.042 us; speedup 1.0000x reference)
//
#include <hip/hip_runtime.h>
#include <hip/hip_bf16.h>
#include <stdint.h>

// Problem constants (match reference)
#define B_SZ 8
#define T_LEN 1024
#define C_DIM 1024
#define M_ROWS (B_SZ * T_LEN)   // 8192
#define NCH 32
#define CHL (T_LEN / NCH)       // 32

typedef unsigned short ushort_t;
typedef __attribute__((ext_vector_type(8))) short short8;
typedef __attribute__((ext_vector_type(4))) float f32x4;
typedef __attribute__((ext_vector_type(4))) unsigned short us4;

static __device__ __forceinline__ float bf2f(ushort_t u) {
  union { unsigned int i; float f; } x; x.i = ((unsigned int)u) << 16; return x.f;
}
static __device__ __forceinline__ ushort_t f2bf(float f) {
  union { float f; unsigned int i; } x; x.f = f;
  unsigned int r = x.i + 0x7fffu + ((x.i >> 16) & 1u);
  return (ushort_t)(r >> 16);
}

static __device__ __forceinline__ void gload_lds16(const void* g, void* l) {
  __builtin_amdgcn_global_load_lds(
      (const __attribute__((address_space(1))) void*)g,
      (__attribute__((address_space(3))) void*)l, 16, 0, 0);
}

// -------- prep: ALL 4 weights -> fragment-major bf16 | xm mix ---------------
// Fragment-major (B-operand of mfma_f32_16x16x32_bf16), R9-verified layout:
//   Wf[mode][nf][kt][l][e]: element = W[16*nf + (l&15)][32*kt + (l>>4)*8 + e]
//   strides e:1, l:8, kt:512, nf:16384, mode:2^20.
// A wave's fragment load (nf,kt) = 64 lanes x 16B CONTIGUOUS (1 KB).
__global__ void prep_kernel(const float* __restrict__ wk, const float* __restrict__ wv,
                            const float* __restrict__ wr, const float* __restrict__ wo,
                            ushort_t* __restrict__ wf,
                            const float* __restrict__ x, const float* __restrict__ tm,
                            const float* __restrict__ cm, ushort_t* __restrict__ xmb) {
  const int bid = blockIdx.x;
  if (bid < 2048) {
    // frag-major pack, 8 elems/thread; g in [0, 524288)
    int g = bid * 256 + threadIdx.x;
    int mode = g >> 17;
    int rem = g & 131071;
    int nf = rem >> 11;
    int rem2 = rem & 2047;
    int kt = rem2 >> 6;
    int l = rem2 & 63;
    const float* src = mode == 0 ? wk : mode == 1 ? wv : mode == 2 ? wr : wo;
    const float* sp = src + (size_t)(nf * 16 + (l & 15)) * C_DIM + kt * 32 + (l >> 4) * 8;
    float4 v0 = *(const float4*)sp;
    float4 v1 = *(const float4*)(sp + 4);
    us4 o0 = {f2bf(v0.x), f2bf(v0.y), f2bf(v0.z), f2bf(v0.w)};
    us4 o1 = {f2bf(v1.x), f2bf(v1.y), f2bf(v1.z), f2bf(v1.w)};
    ushort_t* dst = wf + (size_t)g * 8;
    *(us4*)dst = o0;
    *(us4*)(dst + 4) = o1;
  } else {
    // xm time-shift mix, 4 elems/thread
    int gid = (bid - 2048) * 256 + threadIdx.x;
    int c4 = (gid & (C_DIM / 4 - 1)) * 4;
    int t = (gid >> 8) & (T_LEN - 1);
    const float4 zero = {0.f, 0.f, 0.f, 0.f};
    float4 xv = *(const float4*)(x + (size_t)gid * 4);
    float4 xp = (t > 0) ? *(const float4*)(x + (size_t)gid * 4 - C_DIM) : zero;
    float4 xn = (t < T_LEN - 1) ? *(const float4*)(x + (size_t)gid * 4 + C_DIM) : zero;
    float4 tmv = *(const float4*)(tm + c4);
    float4 cmv = *(const float4*)(cm + c4);
    float4 xc = (c4 < C_DIM / 2) ? xp : xn;
    us4 o;
    o.x = f2bf(xv.x * tmv.x + xp.x * (1.f - tmv.x) + xc.x * cmv.x);
    o.y = f2bf(xv.y * tmv.y + xp.y * (1.f - tmv.y) + xc.y * cmv.y);
    o.z = f2bf(xv.z * tmv.z + xp.z * (1.f - tmv.z) + xc.z * cmv.z);
    o.w = f2bf(xv.w * tmv.w + xp.w * (1.f - tmv.w) + xc.w * cmv.w);
    *(us4*)(xmb + (size_t)gid * 4) = o;
  }
}

// ==== GEMM: 256x128 tile, BK=32, 8 waves, A 3-buf LDS + B frag-major regs ===
// R12 = R11 geometry (both proven levers: counted-vmcnt 3-buf + 128 MFMA per
// drain) + R9's B-to-reg (proven-correct frag-major layout). LDS traffic per
// block-step 88->48 KB (the R11-measured dominant term); LDS 48 KB total ->
// FUSED=1: 768 blocks at 3 blocks/CU = FULLY RESIDENT grid, zero tail.
// FUSED=0 (output GEMM): 256 blocks at 1/CU, even round, mode 3 -> f32.
// Pipeline per iter t: LOADB(t+1) 4x b128; MFMA(t) [A ds_read x4 + B regs];
// stageA(t+2) 2x gload_lds; vmcnt(6) [A(t+1):2 oldest of 8 in flight ->
// drained]; raw s_barrier. Compiler's own b-reg wait (vmcnt(6) at MFMA
// start) drains only LOADB(t) — older than A(t+1). All orderings safe.
// XCD swizzle: xcd=bid&7 owns 4 contiguous 256-row bm-panels (2MB, L2-fit).
// A LDS slot swizzle (R6/R11-verified): phys slot = logical ^ ((row>>1)&3).
template <int FUSED>
__global__ __launch_bounds__(512, 4) void gemm_main(const ushort_t* __restrict__ A,
                                                    const ushort_t* __restrict__ Wf,
                                                    float* __restrict__ outF,
                                                    ushort_t* __restrict__ outK,
                                                    ushort_t* __restrict__ outV,
                                                    ushort_t* __restrict__ outR) {
  constexpr int K = 1024;
  __shared__ ushort_t As[3][256 * 32];   // 48 KB

  const int tid = threadIdx.x;
  const int lane = tid & 63;
  const int wid = tid >> 6;        // 0..7
  const int wm = wid & 3;          // 0..3
  const int wn = wid >> 2;         // 0..1

  const int bid = blockIdx.x;
  const int xcd = bid & 7;
  const int c = bid >> 3;                    // fused 0..95 / out 0..31
  const int bm = (xcd * 4 + (c & 3)) * 256;
  const int jb = c >> 2;                     // fused 0..23 / out 0..7
  const int mode = FUSED ? (jb >> 3) : 3;
  const int bn = FUSED ? (jb & 7) * 128 : jb * 128;

  const int wr = wm * 64;
  const int wc = wn * 64;

  f32x4 acc[4][4];
#pragma unroll
  for (int m = 0; m < 4; ++m)
#pragma unroll
    for (int n = 0; n < 4; ++n) acc[m][n] = (f32x4){0.f, 0.f, 0.f, 0.f};

  // A staging: chunks tid and tid+512 of 1024 16B-chunks; pre-swizzled source
  const int a0r = tid >> 2, a0c = (((tid & 3) ^ ((tid >> 3) & 3)) * 8);
  const int c1 = tid + 512;
  const int a1r = c1 >> 2, a1c = (((c1 & 3) ^ ((c1 >> 3) & 3)) * 8);
  const ushort_t* Ag0 = A + (size_t)(bm + a0r) * K + a0c;
  const ushort_t* Ag1 = A + (size_t)(bm + a1r) * K + a1c;

  // A frag read addressing
  const int fr = lane & 15;
  const int kq = lane >> 4;
  const int ps = (kq ^ ((fr >> 1) & 3)) * 8;

  // B frag-major base: this wave covers nf = nfbase..nfbase+3
  const int nfbase = (bn >> 4) + wn * 4;
  const ushort_t* Bgl = Wf + ((size_t)mode << 20) + (size_t)nfbase * 16384 + lane * 8;

  auto stageA = [&](int buf, int kt) {
    const int k0 = kt * 32;
    gload_lds16(Ag0 + k0, &As[buf][tid * 8]);
    gload_lds16(Ag1 + k0, &As[buf][(tid + 512) * 8]);
  };

  short8 b0[4], b1[4];

#define LOADB(DST, KT)                                                        \
  {                                                                           \
    _Pragma("unroll") for (int n = 0; n < 4; ++n)                             \
        DST[n] = *(const short8*)(Bgl + n * 16384 + (KT)*512);                \
  }

#define MFMA_STEP(ABUF, BREG)                                                 \
  {                                                                           \
    short8 af[4];                                                             \
    _Pragma("unroll") for (int m = 0; m < 4; ++m)                             \
        af[m] = *(const short8*)&As[ABUF][(wr + m * 16 + fr) * 32 + ps];      \
    _Pragma("unroll") for (int m = 0; m < 4; ++m)                             \
        _Pragma("unroll") for (int n = 0; n < 4; ++n)                         \
            acc[m][n] = __builtin_amdgcn_mfma_f32_16x16x32_bf16(              \
                af[m], BREG[n], acc[m][n], 0, 0, 0);                          \
  }

#define ENDSTEP(N)                                                            \
  asm volatile("s_waitcnt vmcnt(" #N ")" ::: "memory");                       \
  __builtin_amdgcn_s_barrier();                                               \
  __builtin_amdgcn_sched_barrier(0);

#define BODY(ACUR, ASTG, BCUR, BNXT, T)                                       \
  LOADB(BNXT, (T) + 1);                                                       \
  MFMA_STEP(ACUR, BCUR);                                                      \
  stageA(ASTG, (T) + 2);                                                      \
  ENDSTEP(6)

  // prologue: A(0), B(0), A(1); vmcnt(2) -> A(0)+B(0) done, A(1) in flight
  stageA(0, 0);
  LOADB(b0, 0);
  stageA(1, 1);
  ENDSTEP(2)

#pragma unroll 1
  for (int i = 0; i < 5; ++i) {
    const int t0 = 6 * i;
    BODY(0, 2, b0, b1, t0 + 0)
    BODY(1, 0, b1, b0, t0 + 1)
    BODY(2, 1, b0, b1, t0 + 2)
    BODY(0, 2, b1, b0, t0 + 3)
    BODY(1, 0, b0, b1, t0 + 4)
    BODY(2, 1, b1, b0, t0 + 5)
  }
  // t=30: A buf0 + b0; load B(31); no stage; full drain
  LOADB(b1, 31);
  MFMA_STEP(0, b0);
  ENDSTEP(0)
  // t=31: A buf1 + b1
  MFMA_STEP(1, b1);

  // ---- epilogue: C/D layout col=lane&15, row=(lane>>4)*4+j ----
#pragma unroll
  for (int m = 0; m < 4; ++m)
#pragma unroll
    for (int n = 0; n < 4; ++n)
#pragma unroll
      for (int j = 0; j < 4; ++j) {
        float v = acc[m][n][j];
        size_t idx = (size_t)(bm + wr + m * 16 + kq * 4 + j) * C_DIM + (bn + wc + n * 16 + fr);
        if (mode == 0) {
          outK[idx] = f2bf(__expf(fminf(v, 60.f)));
        } else if (mode == 1) {
          outV[idx] = f2bf(v);
        } else if (mode == 2) {
          outR[idx] = f2bf(1.f / (1.f + __expf(-v)));
        } else {
          outF[idx] = v;
        }
      }
#undef BODY
#undef ENDSTEP
#undef MFMA_STEP
#undef LOADB
}

// ---------------- wkv chunked scan -----------------------------------------
__global__ void wkv_phaseA(const ushort_t* __restrict__ kk, const ushort_t* __restrict__ vv,
                           const float* __restrict__ td,
                           float* __restrict__ sa, float* __restrict__ sb,
                           float* __restrict__ sp) {
  int gid = blockIdx.x * 256 + threadIdx.x;
  int c = gid & (C_DIM - 1);
  int ch = (gid >> 10) & (NCH - 1);
  int b = gid >> 15;
  float w = td[c] * (1.f / T_LEN);
  size_t base = ((size_t)b * T_LEN + ch * CHL) * C_DIM + c;
  float a = 0.f, bb = 0.f, p = -1e38f;
  for (int t = 0; t < CHL; ++t) {
    float kt = bf2f(kk[base + (size_t)t * C_DIM]);
    float vt = bf2f(vv[base + (size_t)t * C_DIM]);
    float no2 = fmaxf(w + p, kt);
    float e1 = __expf(w + p - no2);
    float e2 = __expf(kt - no2);
    a = e1 * a + e2 * vt;
    bb = e1 * bb + e2;
    p = no2;
  }
  sa[gid] = a; sb[gid] = bb; sp[gid] = p;
}

__global__ void wkv_phaseC2(const ushort_t* __restrict__ kk, const ushort_t* __restrict__ vv,
                            const ushort_t* __restrict__ sr, const float* __restrict__ td,
                            const float* __restrict__ tf,
                            const float* __restrict__ sa, const float* __restrict__ sb,
                            const float* __restrict__ sp, ushort_t* __restrict__ sy) {
  int gid = blockIdx.x * 256 + threadIdx.x;
  int c = gid & (C_DIM - 1);
  int ch = (gid >> 10) & (NCH - 1);
  int b = gid >> 15;
  float w = td[c] * (1.f / T_LEN);
  float u = tf[c] * (1.f / T_LEN);
  float wL = w * (float)CHL;

  float a = 0.f, bb = 0.f, p = -1e38f;
  size_t sbase = ((size_t)b * NCH) * C_DIM + c;
  for (int j = 0; j < ch; ++j) {
    float ac = sa[sbase + (size_t)j * C_DIM];
    float bc = sb[sbase + (size_t)j * C_DIM];
    float pc = sp[sbase + (size_t)j * C_DIM];
    float pn = fmaxf(p + wL, pc);
    float e1 = __expf(p + wL - pn);
    float e2 = __expf(pc - pn);
    a = e1 * a + e2 * ac;
    bb = e1 * bb + e2 * bc;
    p = pn;
  }

  size_t base = ((size_t)b * T_LEN + ch * CHL) * C_DIM + c;
  for (int t = 0; t < CHL; ++t) {
    float kt = bf2f(kk[base + (size_t)t * C_DIM]);
    float vt = bf2f(vv[base + (size_t)t * C_DIM]);
    float no = fmaxf(p, u + kt);
    float e1 = __expf(p - no);
    float e2 = __expf(u + kt - no);
    float y = (e1 * a + e2 * vt) / (e1 * bb + e2);
    float srv = bf2f(sr[base + (size_t)t * C_DIM]);
    sy[base + (size_t)t * C_DIM] = f2bf(srv * y);
    float no2 = fmaxf(w + p, kt);
    e1 = __expf(w + p - no2);
    e2 = __expf(kt - no2);
    a = e1 * a + e2 * vt;
    bb = e1 * bb + e2;
    p = no2;
  }
}

// ---------------------------------------------------------------------------
extern "C" void kernel_launch(void* const* d_in, const int* in_sizes, int n_in,
                              void* d_out, int out_size, void* d_ws, size_t ws_size,
                              hipStream_t stream) {
  const float* x  = (const float*)d_in[0];
  const float* td = (const float*)d_in[1];
  const float* tf = (const float*)d_in[2];
  const float* tm = (const float*)d_in[3];
  const float* cm = (const float*)d_in[4];
  const float* Wk = (const float*)d_in[5];
  const float* Wv = (const float*)d_in[6];
  const float* Wr = (const float*)d_in[7];
  const float* Wo = (const float*)d_in[8];

  const size_t MC = (size_t)M_ROWS * C_DIM;
  const size_t CC = (size_t)C_DIM * C_DIM;

  char* ws = (char*)d_ws;
  ushort_t* xmb = (ushort_t*)ws; ws += MC * 2;
  ushort_t* Wf  = (ushort_t*)ws; ws += 4 * CC * 2;   // all 4 weights frag-major
  ushort_t* kk  = (ushort_t*)ws; ws += MC * 2;
  ushort_t* vv  = (ushort_t*)ws; ws += MC * 2;
  ushort_t* sr  = (ushort_t*)ws; ws += MC * 2;
  ushort_t* sy  = (ushort_t*)ws; ws += MC * 2;
  float* sa = (float*)ws; ws += (size_t)B_SZ * NCH * C_DIM * 4;
  float* sb = (float*)ws; ws += (size_t)B_SZ * NCH * C_DIM * 4;
  float* sp = (float*)ws; ws += (size_t)B_SZ * NCH * C_DIM * 4;

  prep_kernel<<<dim3(10240), 256, 0, stream>>>(Wk, Wv, Wr, Wo, Wf, x, tm, cm, xmb);

  // fused k/v/r projections: 768 blocks @ 3/CU (fully resident), B in regs
  gemm_main<1><<<dim3(768), 512, 0, stream>>>(xmb, Wf, nullptr, kk, vv, sr);

  wkv_phaseA<<<(B_SZ * NCH * C_DIM) / 256, 256, 0, stream>>>(kk, vv, td, sa, sb, sp);
  wkv_phaseC2<<<(B_SZ * NCH * C_DIM) / 256, 256, 0, stream>>>(kk, vv, sr, td, tf, sa, sb, sp, sy);

  // output projection: 256 blocks, same structure, mode 3 -> f32 d_out
  gemm_main<0><<<dim3(256), 512, 0, stream>>>(sy, Wf, (float*)d_out, nullptr, nullptr, nullptr);
}

// Round 13
// 146.971 us; speedup vs baseline: 1.0889x; 1.0889x over previous
//
#include <hip/hip_runtime.h>
#include <hip/hip_bf16.h>
#include <stdint.h>

// Problem constants (match reference)
#define B_SZ 8
#define T_LEN 1024
#define C_DIM 1024
#define M_ROWS (B_SZ * T_LEN)   // 8192
#define NCH 32
#define CHL (T_LEN / NCH)       // 32

typedef unsigned short ushort_t;
typedef __attribute__((ext_vector_type(8))) short short8;
typedef __attribute__((ext_vector_type(4))) float f32x4;
typedef __attribute__((ext_vector_type(4))) unsigned short us4;

static __device__ __forceinline__ float bf2f(ushort_t u) {
  union { unsigned int i; float f; } x; x.i = ((unsigned int)u) << 16; return x.f;
}
static __device__ __forceinline__ ushort_t f2bf(float f) {
  union { float f; unsigned int i; } x; x.f = f;
  unsigned int r = x.i + 0x7fffu + ((x.i >> 16) & 1u);
  return (ushort_t)(r >> 16);
}

static __device__ __forceinline__ void gload_lds16(const void* g, void* l) {
  __builtin_amdgcn_global_load_lds(
      (const __attribute__((address_space(1))) void*)g,
      (__attribute__((address_space(3))) void*)l, 16, 0, 0);
}

// -------- merged prep: weight f32->bf16 (4 mats) + time-shift mix ----------
__global__ void prep_kernel(const float* __restrict__ wk, const float* __restrict__ wv,
                            const float* __restrict__ wr, const float* __restrict__ wo,
                            ushort_t* __restrict__ wout,
                            const float* __restrict__ x, const float* __restrict__ tm,
                            const float* __restrict__ cm, ushort_t* __restrict__ xmb) {
  if (blockIdx.x < 4096) {
    int gid = blockIdx.x * 256 + threadIdx.x;
    int which = gid >> 18;
    int off = (gid << 2) & ((1 << 20) - 1);
    const float* src = which == 0 ? wk : which == 1 ? wv : which == 2 ? wr : wo;
    float4 v = *(const float4*)(src + off);
    us4 o = {f2bf(v.x), f2bf(v.y), f2bf(v.z), f2bf(v.w)};
    *(us4*)(wout + (size_t)gid * 4) = o;
  } else {
    int gid = (blockIdx.x - 4096) * 256 + threadIdx.x;
    int c4 = (gid & (C_DIM / 4 - 1)) * 4;
    int t = (gid >> 8) & (T_LEN - 1);
    const float4 zero = {0.f, 0.f, 0.f, 0.f};
    float4 xv = *(const float4*)(x + (size_t)gid * 4);
    float4 xp = (t > 0) ? *(const float4*)(x + (size_t)gid * 4 - C_DIM) : zero;
    float4 xn = (t < T_LEN - 1) ? *(const float4*)(x + (size_t)gid * 4 + C_DIM) : zero;
    float4 tmv = *(const float4*)(tm + c4);
    float4 cmv = *(const float4*)(cm + c4);
    float4 xc = (c4 < C_DIM / 2) ? xp : xn;
    us4 o;
    o.x = f2bf(xv.x * tmv.x + xp.x * (1.f - tmv.x) + xc.x * cmv.x);
    o.y = f2bf(xv.y * tmv.y + xp.y * (1.f - tmv.y) + xc.y * cmv.y);
    o.z = f2bf(xv.z * tmv.z + xp.z * (1.f - tmv.z) + xc.z * cmv.z);
    o.w = f2bf(xv.w * tmv.w + xp.w * (1.f - tmv.w) + xc.w * cmv.w);
    *(us4*)(xmb + (size_t)gid * 4) = o;
  }
}

// ==== fused k/v/r GEMM: 256x128, BK=32, 8 waves, 3-buf counted vmcnt ========
// R11 structure verbatim (best: fused 88us / 586 TF) + ONE change: T5
// s_setprio(1) around the MFMA cluster. Gate rationale (m218b/m224): counted
// vmcnt keeps loads in flight across barriers and 2 co-resident blocks give
// wave role-diversity (stage-issuing vs MFMA-entering) -> scheduler can
// prefer MFMA waves. (m190: null/harmful only on lockstep full-drain.)
__global__ __launch_bounds__(512, 4) void gemm_fused(const ushort_t* __restrict__ A,
                                                     const ushort_t* __restrict__ Bw,
                                                     ushort_t* __restrict__ outK,
                                                     ushort_t* __restrict__ outV,
                                                     ushort_t* __restrict__ outR) {
  constexpr int K = 1024;
  __shared__ ushort_t As[3][256 * 32];   // 48 KB
  __shared__ ushort_t Bs[3][128 * 32];   // 24 KB

  const int tid = threadIdx.x;
  const int lane = tid & 63;
  const int wid = tid >> 6;        // 0..7
  const int wm = wid & 3;          // 0..3
  const int wn = wid >> 2;         // 0..1

  const int bid = blockIdx.x;
  const int xcd = bid & 7;
  const int c = bid >> 3;                    // 0..95
  const int bm = (xcd * 4 + (c & 3)) * 256;
  const int jb = c >> 2;                     // 0..23
  const int mode = jb >> 3;                  // 0:k 1:v 2:r
  const int bn = (jb & 7) * 128;
  const ushort_t* Bp = Bw + ((size_t)mode << 20);

  const int wr = wm * 64;
  const int wc = wn * 64;

  f32x4 acc[4][4];
#pragma unroll
  for (int m = 0; m < 4; ++m)
#pragma unroll
    for (int n = 0; n < 4; ++n) acc[m][n] = (f32x4){0.f, 0.f, 0.f, 0.f};

  // staging: A chunks c0=tid, c1=tid+512 (1024 total); B chunk cb=tid (512)
  const int a0r = tid >> 2, a0c = (((tid & 3) ^ ((tid >> 3) & 3)) * 8);
  const int c1 = tid + 512;
  const int a1r = c1 >> 2, a1c = (((c1 & 3) ^ ((c1 >> 3) & 3)) * 8);
  const ushort_t* Ag0 = A + (size_t)(bm + a0r) * K + a0c;
  const ushort_t* Ag1 = A + (size_t)(bm + a1r) * K + a1c;
  const ushort_t* Bg = Bp + (size_t)(bn + a0r) * K + a0c;   // rows 0..127

  // frag read addressing
  const int fr = lane & 15;
  const int kq = lane >> 4;
  const int ps = (kq ^ ((fr >> 1) & 3)) * 8;

  auto stage = [&](int buf, int kt) {
    const int k0 = kt * 32;
    gload_lds16(Ag0 + k0, &As[buf][tid * 8]);
    gload_lds16(Ag1 + k0, &As[buf][(tid + 512) * 8]);
    gload_lds16(Bg + k0, &Bs[buf][tid * 8]);
  };

#define MFMA_STEP(BUF)                                                        \
  {                                                                           \
    short8 af[4], bfr[4];                                                     \
    _Pragma("unroll") for (int m = 0; m < 4; ++m)                             \
        af[m] = *(const short8*)&As[BUF][(wr + m * 16 + fr) * 32 + ps];       \
    _Pragma("unroll") for (int n = 0; n < 4; ++n)                             \
        bfr[n] = *(const short8*)&Bs[BUF][(wc + n * 16 + fr) * 32 + ps];      \
    __builtin_amdgcn_s_setprio(1);                                            \
    _Pragma("unroll") for (int m = 0; m < 4; ++m)                             \
        _Pragma("unroll") for (int n = 0; n < 4; ++n)                         \
            acc[m][n] = __builtin_amdgcn_mfma_f32_16x16x32_bf16(              \
                af[m], bfr[n], acc[m][n], 0, 0, 0);                           \
    __builtin_amdgcn_s_setprio(0);                                            \
  }

#define ENDSTEP(N)                                                            \
  asm volatile("s_waitcnt vmcnt(" #N ")" ::: "memory");                       \
  __builtin_amdgcn_s_barrier();                                               \
  __builtin_amdgcn_sched_barrier(0);

#define BODY(ACUR, ASTG, T)                                                   \
  stage(ASTG, (T) + 2);                                                       \
  MFMA_STEP(ACUR);                                                            \
  ENDSTEP(3)

  // prologue: tiles 0,1 in flight (6 loads); vmcnt(3) -> tile0 done
  stage(0, 0);
  stage(1, 1);
  ENDSTEP(3)

#pragma unroll 1
  for (int i = 0; i < 10; ++i) {
    const int t0 = 3 * i;
    BODY(0, 2, t0 + 0)
    BODY(1, 0, t0 + 1)
    BODY(2, 1, t0 + 2)
  }
  // t=30: reads buf0; stage(31) still in flight -> full drain
  MFMA_STEP(0);
  ENDSTEP(0)
  // t=31: reads buf1
  MFMA_STEP(1);

  // ---- epilogue: C/D layout col=lane&15, row=(lane>>4)*4+j ----
#pragma unroll
  for (int m = 0; m < 4; ++m)
#pragma unroll
    for (int n = 0; n < 4; ++n)
#pragma unroll
      for (int j = 0; j < 4; ++j) {
        float v = acc[m][n][j];
        size_t idx = (size_t)(bm + wr + m * 16 + kq * 4 + j) * C_DIM + (bn + wc + n * 16 + fr);
        if (mode == 0) {
          outK[idx] = f2bf(__expf(fminf(v, 60.f)));
        } else if (mode == 1) {
          outV[idx] = f2bf(v);
        } else {
          outR[idx] = f2bf(1.f / (1.f + __expf(-v)));
        }
      }
#undef BODY
#undef ENDSTEP
#undef MFMA_STEP
}

// ============ output GEMM: 128x128 tile, BK=64, 2-phase (R11 form, kept) ====
__global__ __launch_bounds__(256, 2) void gemm_out(const ushort_t* __restrict__ A,
                                                   const ushort_t* __restrict__ Bw,
                                                   float* __restrict__ outF) {
  constexpr int K = 1024;
  constexpr int NT = K / 64;
  __shared__ ushort_t As[2][128 * 64];
  __shared__ ushort_t Bs[2][128 * 64];

  const int tid = threadIdx.x;
  const int l = tid & 63;
  const int wave = tid >> 6;
  const int fr = l & 15;
  const int kq = l >> 4;

  const int bid = blockIdx.x;
  const int xcd = bid & 7;
  const int idx = bid >> 3;
  const int jb = idx >> 3;
  const int bm = (xcd * 8 + (idx & 7)) * 128;
  const int bn = jb * 128;

  const int wr = (wave >> 1) * 64;
  const int wc = (wave & 1) * 64;

  f32x4 acc[4][4];
#pragma unroll
  for (int m = 0; m < 4; ++m)
#pragma unroll
    for (int n = 0; n < 4; ++n) acc[m][n] = (f32x4){0.f, 0.f, 0.f, 0.f};

  int srow[4], scol[4];
#pragma unroll
  for (int j = 0; j < 4; ++j) {
    int row = wave * 32 + j * 8 + (l >> 3);
    srow[j] = row;
    scol[j] = ((l & 7) ^ (row & 7)) * 8;
  }
  const ushort_t* AgB = A + (size_t)bm * K;
  const ushort_t* BgB = Bw + (size_t)bn * K;
  const int dst0 = wave * 2048 + l * 8;

  auto stage = [&](int buf, int k0) {
#pragma unroll
    for (int j = 0; j < 4; ++j)
      gload_lds16(AgB + (size_t)srow[j] * K + scol[j] + k0, &As[buf][dst0 + j * 512]);
#pragma unroll
    for (int j = 0; j < 4; ++j)
      gload_lds16(BgB + (size_t)srow[j] * K + scol[j] + k0, &Bs[buf][dst0 + j * 512]);
  };

  stage(0, 0);
  asm volatile("s_waitcnt vmcnt(0)" ::: "memory");
  __syncthreads();

  const int ps0 = ((0 * 4 + kq) ^ (fr & 7)) * 8;
  const int ps1 = ((1 * 4 + kq) ^ (fr & 7)) * 8;

  int cur = 0;
  for (int t = 0; t < NT; ++t) {
    if (t < NT - 1) stage(cur ^ 1, (t + 1) * 64);
    short8 af[4][2], bfr[4][2];
#pragma unroll
    for (int m = 0; m < 4; ++m) {
      af[m][0] = *(const short8*)&As[cur][(wr + m * 16 + fr) * 64 + ps0];
      af[m][1] = *(const short8*)&As[cur][(wr + m * 16 + fr) * 64 + ps1];
    }
#pragma unroll
    for (int n = 0; n < 4; ++n) {
      bfr[n][0] = *(const short8*)&Bs[cur][(wc + n * 16 + fr) * 64 + ps0];
      bfr[n][1] = *(const short8*)&Bs[cur][(wc + n * 16 + fr) * 64 + ps1];
    }
#pragma unroll
    for (int m = 0; m < 4; ++m)
#pragma unroll
      for (int n = 0; n < 4; ++n)
#pragma unroll
        for (int ks = 0; ks < 2; ++ks)
          acc[m][n] = __builtin_amdgcn_mfma_f32_16x16x32_bf16(af[m][ks], bfr[n][ks], acc[m][n], 0, 0, 0);
    asm volatile("s_waitcnt vmcnt(0)" ::: "memory");
    __syncthreads();
    cur ^= 1;
  }

#pragma unroll
  for (int m = 0; m < 4; ++m)
#pragma unroll
    for (int n = 0; n < 4; ++n)
#pragma unroll
      for (int j = 0; j < 4; ++j)
        outF[(size_t)(bm + wr + m * 16 + kq * 4 + j) * C_DIM + (bn + wc + n * 16 + fr)] =
            acc[m][n][j];
}

// ---------------- wkv chunked scan -----------------------------------------
__global__ void wkv_phaseA(const ushort_t* __restrict__ kk, const ushort_t* __restrict__ vv,
                           const float* __restrict__ td,
                           float* __restrict__ sa, float* __restrict__ sb,
                           float* __restrict__ sp) {
  int gid = blockIdx.x * 256 + threadIdx.x;
  int c = gid & (C_DIM - 1);
  int ch = (gid >> 10) & (NCH - 1);
  int b = gid >> 15;
  float w = td[c] * (1.f / T_LEN);
  size_t base = ((size_t)b * T_LEN + ch * CHL) * C_DIM + c;
  float a = 0.f, bb = 0.f, p = -1e38f;
  for (int t = 0; t < CHL; ++t) {
    float kt = bf2f(kk[base + (size_t)t * C_DIM]);
    float vt = bf2f(vv[base + (size_t)t * C_DIM]);
    float no2 = fmaxf(w + p, kt);
    float e1 = __expf(w + p - no2);
    float e2 = __expf(kt - no2);
    a = e1 * a + e2 * vt;
    bb = e1 * bb + e2;
    p = no2;
  }
  sa[gid] = a; sb[gid] = bb; sp[gid] = p;
}

__global__ void wkv_phaseC2(const ushort_t* __restrict__ kk, const ushort_t* __restrict__ vv,
                            const ushort_t* __restrict__ sr, const float* __restrict__ td,
                            const float* __restrict__ tf,
                            const float* __restrict__ sa, const float* __restrict__ sb,
                            const float* __restrict__ sp, ushort_t* __restrict__ sy) {
  int gid = blockIdx.x * 256 + threadIdx.x;
  int c = gid & (C_DIM - 1);
  int ch = (gid >> 10) & (NCH - 1);
  int b = gid >> 15;
  float w = td[c] * (1.f / T_LEN);
  float u = tf[c] * (1.f / T_LEN);
  float wL = w * (float)CHL;

  float a = 0.f, bb = 0.f, p = -1e38f;
  size_t sbase = ((size_t)b * NCH) * C_DIM + c;
  for (int j = 0; j < ch; ++j) {
    float ac = sa[sbase + (size_t)j * C_DIM];
    float bc = sb[sbase + (size_t)j * C_DIM];
    float pc = sp[sbase + (size_t)j * C_DIM];
    float pn = fmaxf(p + wL, pc);
    float e1 = __expf(p + wL - pn);
    float e2 = __expf(pc - pn);
    a = e1 * a + e2 * ac;
    bb = e1 * bb + e2 * bc;
    p = pn;
  }

  size_t base = ((size_t)b * T_LEN + ch * CHL) * C_DIM + c;
  for (int t = 0; t < CHL; ++t) {
    float kt = bf2f(kk[base + (size_t)t * C_DIM]);
    float vt = bf2f(vv[base + (size_t)t * C_DIM]);
    float no = fmaxf(p, u + kt);
    float e1 = __expf(p - no);
    float e2 = __expf(u + kt - no);
    float y = (e1 * a + e2 * vt) / (e1 * bb + e2);
    float srv = bf2f(sr[base + (size_t)t * C_DIM]);
    sy[base + (size_t)t * C_DIM] = f2bf(srv * y);
    float no2 = fmaxf(w + p, kt);
    e1 = __expf(w + p - no2);
    e2 = __expf(kt - no2);
    a = e1 * a + e2 * vt;
    bb = e1 * bb + e2;
    p = no2;
  }
}

// ---------------------------------------------------------------------------
extern "C" void kernel_launch(void* const* d_in, const int* in_sizes, int n_in,
                              void* d_out, int out_size, void* d_ws, size_t ws_size,
                              hipStream_t stream) {
  const float* x  = (const float*)d_in[0];
  const float* td = (const float*)d_in[1];
  const float* tf = (const float*)d_in[2];
  const float* tm = (const float*)d_in[3];
  const float* cm = (const float*)d_in[4];
  const float* Wk = (const float*)d_in[5];
  const float* Wv = (const float*)d_in[6];
  const float* Wr = (const float*)d_in[7];
  const float* Wo = (const float*)d_in[8];

  const size_t MC = (size_t)M_ROWS * C_DIM;
  const size_t CC = (size_t)C_DIM * C_DIM;

  char* ws = (char*)d_ws;
  ushort_t* xmb = (ushort_t*)ws; ws += MC * 2;
  ushort_t* Wb  = (ushort_t*)ws; ws += 4 * CC * 2;
  ushort_t* kk  = (ushort_t*)ws; ws += MC * 2;
  ushort_t* vv  = (ushort_t*)ws; ws += MC * 2;
  ushort_t* sr  = (ushort_t*)ws; ws += MC * 2;
  ushort_t* sy  = (ushort_t*)ws; ws += MC * 2;
  float* sa = (float*)ws; ws += (size_t)B_SZ * NCH * C_DIM * 4;
  float* sb = (float*)ws; ws += (size_t)B_SZ * NCH * C_DIM * 4;
  float* sp = (float*)ws; ws += (size_t)B_SZ * NCH * C_DIM * 4;

  prep_kernel<<<dim3(12288), 256, 0, stream>>>(Wk, Wv, Wr, Wo, Wb, x, tm, cm, xmb);

  // fused k/v/r projections: 256x128 tiles, 768 blocks, 3-buf counted vmcnt
  gemm_fused<<<dim3(768), 512, 0, stream>>>(xmb, Wb, kk, vv, sr);

  wkv_phaseA<<<(B_SZ * NCH * C_DIM) / 256, 256, 0, stream>>>(kk, vv, td, sa, sb, sp);
  wkv_phaseC2<<<(B_SZ * NCH * C_DIM) / 256, 256, 0, stream>>>(kk, vv, sr, td, tf, sa, sb, sp, sy);

  // output projection: BK=64 2-phase, 512 blocks, XCD-swizzled
  gemm_out<<<dim3(512), 256, 0, stream>>>(sy, Wb + 3 * CC, (float*)d_out);
}

// Round 14
// 146.190 us; speedup vs baseline: 1.0948x; 1.0053x over previous
//
#include <hip/hip_runtime.h>
#include <hip/hip_bf16.h>
#include <stdint.h>

// Problem constants (match reference)
#define B_SZ 8
#define T_LEN 1024
#define C_DIM 1024
#define M_ROWS (B_SZ * T_LEN)   // 8192
#define NCH 32
#define CHL (T_LEN / NCH)       // 32

typedef unsigned short ushort_t;
typedef __attribute__((ext_vector_type(8))) short short8;
typedef __attribute__((ext_vector_type(4))) float f32x4;
typedef __attribute__((ext_vector_type(4))) unsigned short us4;

static __device__ __forceinline__ float bf2f(ushort_t u) {
  union { unsigned int i; float f; } x; x.i = ((unsigned int)u) << 16; return x.f;
}
static __device__ __forceinline__ ushort_t f2bf(float f) {
  union { float f; unsigned int i; } x; x.f = f;
  unsigned int r = x.i + 0x7fffu + ((x.i >> 16) & 1u);
  return (ushort_t)(r >> 16);
}

static __device__ __forceinline__ void gload_lds16(const void* g, void* l) {
  __builtin_amdgcn_global_load_lds(
      (const __attribute__((address_space(1))) void*)g,
      (__attribute__((address_space(3))) void*)l, 16, 0, 0);
}

// -------- merged prep: weight f32->bf16 (4 mats) + time-shift mix ----------
__global__ void prep_kernel(const float* __restrict__ wk, const float* __restrict__ wv,
                            const float* __restrict__ wr, const float* __restrict__ wo,
                            ushort_t* __restrict__ wout,
                            const float* __restrict__ x, const float* __restrict__ tm,
                            const float* __restrict__ cm, ushort_t* __restrict__ xmb) {
  if (blockIdx.x < 4096) {
    int gid = blockIdx.x * 256 + threadIdx.x;
    int which = gid >> 18;
    int off = (gid << 2) & ((1 << 20) - 1);
    const float* src = which == 0 ? wk : which == 1 ? wv : which == 2 ? wr : wo;
    float4 v = *(const float4*)(src + off);
    us4 o = {f2bf(v.x), f2bf(v.y), f2bf(v.z), f2bf(v.w)};
    *(us4*)(wout + (size_t)gid * 4) = o;
  } else {
    int gid = (blockIdx.x - 4096) * 256 + threadIdx.x;
    int c4 = (gid & (C_DIM / 4 - 1)) * 4;
    int t = (gid >> 8) & (T_LEN - 1);
    const float4 zero = {0.f, 0.f, 0.f, 0.f};
    float4 xv = *(const float4*)(x + (size_t)gid * 4);
    float4 xp = (t > 0) ? *(const float4*)(x + (size_t)gid * 4 - C_DIM) : zero;
    float4 xn = (t < T_LEN - 1) ? *(const float4*)(x + (size_t)gid * 4 + C_DIM) : zero;
    float4 tmv = *(const float4*)(tm + c4);
    float4 cmv = *(const float4*)(cm + c4);
    float4 xc = (c4 < C_DIM / 2) ? xp : xn;
    us4 o;
    o.x = f2bf(xv.x * tmv.x + xp.x * (1.f - tmv.x) + xc.x * cmv.x);
    o.y = f2bf(xv.y * tmv.y + xp.y * (1.f - tmv.y) + xc.y * cmv.y);
    o.z = f2bf(xv.z * tmv.z + xp.z * (1.f - tmv.z) + xc.z * cmv.z);
    o.w = f2bf(xv.w * tmv.w + xp.w * (1.f - tmv.w) + xc.w * cmv.w);
    *(us4*)(xmb + (size_t)gid * 4) = o;
  }
}

// ==== fused k/v/r GEMM: 256x128, BK=32, 8 waves, 3-buf counted vmcnt ========
// Exact R11 structure (measured best: fused 88us / 586 TF, total 144.6).
// Levers: counted-vmcnt 3-buf (R4->R6) + 128 MFMA per drain at 2 blocks/CU
// (R11). setprio REVERTED (R13: null/-2us — lockstep barrier structure).
__global__ __launch_bounds__(512, 4) void gemm_fused(const ushort_t* __restrict__ A,
                                                     const ushort_t* __restrict__ Bw,
                                                     ushort_t* __restrict__ outK,
                                                     ushort_t* __restrict__ outV,
                                                     ushort_t* __restrict__ outR) {
  constexpr int K = 1024;
  __shared__ ushort_t As[3][256 * 32];   // 48 KB
  __shared__ ushort_t Bs[3][128 * 32];   // 24 KB

  const int tid = threadIdx.x;
  const int lane = tid & 63;
  const int wid = tid >> 6;        // 0..7
  const int wm = wid & 3;          // 0..3
  const int wn = wid >> 2;         // 0..1

  const int bid = blockIdx.x;
  const int xcd = bid & 7;
  const int c = bid >> 3;                    // 0..95
  const int bm = (xcd * 4 + (c & 3)) * 256;
  const int jb = c >> 2;                     // 0..23
  const int mode = jb >> 3;                  // 0:k 1:v 2:r
  const int bn = (jb & 7) * 128;
  const ushort_t* Bp = Bw + ((size_t)mode << 20);

  const int wr = wm * 64;
  const int wc = wn * 64;

  f32x4 acc[4][4];
#pragma unroll
  for (int m = 0; m < 4; ++m)
#pragma unroll
    for (int n = 0; n < 4; ++n) acc[m][n] = (f32x4){0.f, 0.f, 0.f, 0.f};

  // staging: A chunks c0=tid, c1=tid+512 (1024 total); B chunk cb=tid (512)
  const int a0r = tid >> 2, a0c = (((tid & 3) ^ ((tid >> 3) & 3)) * 8);
  const int c1 = tid + 512;
  const int a1r = c1 >> 2, a1c = (((c1 & 3) ^ ((c1 >> 3) & 3)) * 8);
  const ushort_t* Ag0 = A + (size_t)(bm + a0r) * K + a0c;
  const ushort_t* Ag1 = A + (size_t)(bm + a1r) * K + a1c;
  const ushort_t* Bg = Bp + (size_t)(bn + a0r) * K + a0c;   // rows 0..127

  // frag read addressing
  const int fr = lane & 15;
  const int kq = lane >> 4;
  const int ps = (kq ^ ((fr >> 1) & 3)) * 8;

  auto stage = [&](int buf, int kt) {
    const int k0 = kt * 32;
    gload_lds16(Ag0 + k0, &As[buf][tid * 8]);
    gload_lds16(Ag1 + k0, &As[buf][(tid + 512) * 8]);
    gload_lds16(Bg + k0, &Bs[buf][tid * 8]);
  };

#define MFMA_STEP(BUF)                                                        \
  {                                                                           \
    short8 af[4], bfr[4];                                                     \
    _Pragma("unroll") for (int m = 0; m < 4; ++m)                             \
        af[m] = *(const short8*)&As[BUF][(wr + m * 16 + fr) * 32 + ps];       \
    _Pragma("unroll") for (int n = 0; n < 4; ++n)                             \
        bfr[n] = *(const short8*)&Bs[BUF][(wc + n * 16 + fr) * 32 + ps];      \
    _Pragma("unroll") for (int m = 0; m < 4; ++m)                             \
        _Pragma("unroll") for (int n = 0; n < 4; ++n)                         \
            acc[m][n] = __builtin_amdgcn_mfma_f32_16x16x32_bf16(              \
                af[m], bfr[n], acc[m][n], 0, 0, 0);                           \
  }

#define ENDSTEP(N)                                                            \
  asm volatile("s_waitcnt vmcnt(" #N ")" ::: "memory");                       \
  __builtin_amdgcn_s_barrier();                                               \
  __builtin_amdgcn_sched_barrier(0);

#define BODY(ACUR, ASTG, T)                                                   \
  stage(ASTG, (T) + 2);                                                       \
  MFMA_STEP(ACUR);                                                            \
  ENDSTEP(3)

  // prologue: tiles 0,1 in flight (6 loads); vmcnt(3) -> tile0 done
  stage(0, 0);
  stage(1, 1);
  ENDSTEP(3)

#pragma unroll 1
  for (int i = 0; i < 10; ++i) {
    const int t0 = 3 * i;
    BODY(0, 2, t0 + 0)
    BODY(1, 0, t0 + 1)
    BODY(2, 1, t0 + 2)
  }
  // t=30: reads buf0; stage(31) still in flight -> full drain
  MFMA_STEP(0);
  ENDSTEP(0)
  // t=31: reads buf1
  MFMA_STEP(1);

  // ---- epilogue: C/D layout col=lane&15, row=(lane>>4)*4+j ----
#pragma unroll
  for (int m = 0; m < 4; ++m)
#pragma unroll
    for (int n = 0; n < 4; ++n)
#pragma unroll
      for (int j = 0; j < 4; ++j) {
        float v = acc[m][n][j];
        size_t idx = (size_t)(bm + wr + m * 16 + kq * 4 + j) * C_DIM + (bn + wc + n * 16 + fr);
        if (mode == 0) {
          outK[idx] = f2bf(__expf(fminf(v, 60.f)));
        } else if (mode == 1) {
          outV[idx] = f2bf(v);
        } else {
          outR[idx] = f2bf(1.f / (1.f + __expf(-v)));
        }
      }
#undef BODY
#undef ENDSTEP
#undef MFMA_STEP
}

// ==== output GEMM: R6 structure verbatim (128x128, BK=32, 3-buf, vmcnt(4)),
// mode-3 f32 epilogue. 512 blocks at 3 blocks/CU (48KB LDS) = FULLY RESIDENT
// (capacity 768) — no rounds. R6 measured 536 TF vs BK64-2phase's 381 TF on
// the identical-shape fused workload (R6 vs R10, within-rocprof). ===========
__global__ __launch_bounds__(256, 3) void gemm_out(const ushort_t* __restrict__ A,
                                                   const ushort_t* __restrict__ Bw,
                                                   float* __restrict__ outF) {
  constexpr int K = 1024;
  constexpr int NT = K / 32;
  __shared__ ushort_t As[3][128 * 32];
  __shared__ ushort_t Bs[3][128 * 32];

  const int tid = threadIdx.x;
  const int lane = tid & 63;
  const int wave = tid >> 6;

  const int bid = blockIdx.x;
  const int xcd = bid & 7;
  const int r = bid >> 3;                // 0..63
  const int bm = (xcd * 8 + (r & 7)) * 128;
  const int bn = (r >> 3) * 128;

  const int wr = (wave >> 1) * 64;
  const int wc = (wave & 1) * 64;

  f32x4 acc[4][4];
#pragma unroll
  for (int m = 0; m < 4; ++m)
#pragma unroll
    for (int n = 0; n < 4; ++n) acc[m][n] = (f32x4){0.f, 0.f, 0.f, 0.f};

  const int srow = tid >> 2;
  const int scol = (((tid & 3) ^ ((srow >> 1) & 3)) * 8);
  const ushort_t* Ag = A + (size_t)(bm + srow) * K + scol;
  const ushort_t* Bg = Bw + (size_t)(bn + srow) * K + scol;

  const int fr = lane & 15;
  const int kq = lane >> 4;
  const int ps = (kq ^ ((fr >> 1) & 3)) * 8;

  auto stage = [&](int buf, int kt) {
    const int k0 = kt * 32;
    ushort_t* ap = &As[buf][tid * 8];
    ushort_t* bp = &Bs[buf][tid * 8];
    gload_lds16(Ag + k0, ap);
    gload_lds16(Ag + (size_t)64 * K + k0, ap + 64 * 32);
    gload_lds16(Bg + k0, bp);
    gload_lds16(Bg + (size_t)64 * K + k0, bp + 64 * 32);
  };

  // prologue: buf0, buf1 in flight; wait only for buf0 (vmcnt(4))
  stage(0, 0);
  stage(1, 1);
  asm volatile("s_waitcnt vmcnt(4)" ::: "memory");
  __builtin_amdgcn_s_barrier();
  __builtin_amdgcn_sched_barrier(0);

  int cur = 0, nxt2 = 2;
#pragma unroll 1
  for (int t = 0; t < NT; ++t) {
    if (t + 2 < NT) stage(nxt2, t + 2);
    const ushort_t* asb = &As[cur][0];
    const ushort_t* bsb = &Bs[cur][0];
    short8 af[4], bfr[4];
#pragma unroll
    for (int m = 0; m < 4; ++m)
      af[m] = *(const short8*)&asb[(wr + m * 16 + fr) * 32 + ps];
#pragma unroll
    for (int n = 0; n < 4; ++n)
      bfr[n] = *(const short8*)&bsb[(wc + n * 16 + fr) * 32 + ps];
#pragma unroll
    for (int m = 0; m < 4; ++m)
#pragma unroll
      for (int n = 0; n < 4; ++n)
        acc[m][n] = __builtin_amdgcn_mfma_f32_16x16x32_bf16(af[m], bfr[n], acc[m][n], 0, 0, 0);
    if (t + 2 < NT) {
      asm volatile("s_waitcnt vmcnt(4)" ::: "memory");
    } else {
      asm volatile("s_waitcnt vmcnt(0)" ::: "memory");
    }
    __builtin_amdgcn_s_barrier();
    __builtin_amdgcn_sched_barrier(0);
    cur = (cur == 2) ? 0 : cur + 1;
    nxt2 = (nxt2 == 2) ? 0 : nxt2 + 1;
  }

#pragma unroll
  for (int m = 0; m < 4; ++m)
#pragma unroll
    for (int n = 0; n < 4; ++n)
#pragma unroll
      for (int j = 0; j < 4; ++j)
        outF[(size_t)(bm + wr + m * 16 + kq * 4 + j) * C_DIM + (bn + wc + n * 16 + fr)] =
            acc[m][n][j];
}

// ---------------- wkv chunked scan -----------------------------------------
__global__ void wkv_phaseA(const ushort_t* __restrict__ kk, const ushort_t* __restrict__ vv,
                           const float* __restrict__ td,
                           float* __restrict__ sa, float* __restrict__ sb,
                           float* __restrict__ sp) {
  int gid = blockIdx.x * 256 + threadIdx.x;
  int c = gid & (C_DIM - 1);
  int ch = (gid >> 10) & (NCH - 1);
  int b = gid >> 15;
  float w = td[c] * (1.f / T_LEN);
  size_t base = ((size_t)b * T_LEN + ch * CHL) * C_DIM + c;
  float a = 0.f, bb = 0.f, p = -1e38f;
  for (int t = 0; t < CHL; ++t) {
    float kt = bf2f(kk[base + (size_t)t * C_DIM]);
    float vt = bf2f(vv[base + (size_t)t * C_DIM]);
    float no2 = fmaxf(w + p, kt);
    float e1 = __expf(w + p - no2);
    float e2 = __expf(kt - no2);
    a = e1 * a + e2 * vt;
    bb = e1 * bb + e2;
    p = no2;
  }
  sa[gid] = a; sb[gid] = bb; sp[gid] = p;
}

__global__ void wkv_phaseC2(const ushort_t* __restrict__ kk, const ushort_t* __restrict__ vv,
                            const ushort_t* __restrict__ sr, const float* __restrict__ td,
                            const float* __restrict__ tf,
                            const float* __restrict__ sa, const float* __restrict__ sb,
                            const float* __restrict__ sp, ushort_t* __restrict__ sy) {
  int gid = blockIdx.x * 256 + threadIdx.x;
  int c = gid & (C_DIM - 1);
  int ch = (gid >> 10) & (NCH - 1);
  int b = gid >> 15;
  float w = td[c] * (1.f / T_LEN);
  float u = tf[c] * (1.f / T_LEN);
  float wL = w * (float)CHL;

  float a = 0.f, bb = 0.f, p = -1e38f;
  size_t sbase = ((size_t)b * NCH) * C_DIM + c;
  for (int j = 0; j < ch; ++j) {
    float ac = sa[sbase + (size_t)j * C_DIM];
    float bc = sb[sbase + (size_t)j * C_DIM];
    float pc = sp[sbase + (size_t)j * C_DIM];
    float pn = fmaxf(p + wL, pc);
    float e1 = __expf(p + wL - pn);
    float e2 = __expf(pc - pn);
    a = e1 * a + e2 * ac;
    bb = e1 * bb + e2 * bc;
    p = pn;
  }

  size_t base = ((size_t)b * T_LEN + ch * CHL) * C_DIM + c;
  for (int t = 0; t < CHL; ++t) {
    float kt = bf2f(kk[base + (size_t)t * C_DIM]);
    float vt = bf2f(vv[base + (size_t)t * C_DIM]);
    float no = fmaxf(p, u + kt);
    float e1 = __expf(p - no);
    float e2 = __expf(u + kt - no);
    float y = (e1 * a + e2 * vt) / (e1 * bb + e2);
    float srv = bf2f(sr[base + (size_t)t * C_DIM]);
    sy[base + (size_t)t * C_DIM] = f2bf(srv * y);
    float no2 = fmaxf(w + p, kt);
    e1 = __expf(w + p - no2);
    e2 = __expf(kt - no2);
    a = e1 * a + e2 * vt;
    bb = e1 * bb + e2;
    p = no2;
  }
}

// ---------------------------------------------------------------------------
extern "C" void kernel_launch(void* const* d_in, const int* in_sizes, int n_in,
                              void* d_out, int out_size, void* d_ws, size_t ws_size,
                              hipStream_t stream) {
  const float* x  = (const float*)d_in[0];
  const float* td = (const float*)d_in[1];
  const float* tf = (const float*)d_in[2];
  const float* tm = (const float*)d_in[3];
  const float* cm = (const float*)d_in[4];
  const float* Wk = (const float*)d_in[5];
  const float* Wv = (const float*)d_in[6];
  const float* Wr = (const float*)d_in[7];
  const float* Wo = (const float*)d_in[8];

  const size_t MC = (size_t)M_ROWS * C_DIM;
  const size_t CC = (size_t)C_DIM * C_DIM;

  char* ws = (char*)d_ws;
  ushort_t* xmb = (ushort_t*)ws; ws += MC * 2;
  ushort_t* Wb  = (ushort_t*)ws; ws += 4 * CC * 2;
  ushort_t* kk  = (ushort_t*)ws; ws += MC * 2;
  ushort_t* vv  = (ushort_t*)ws; ws += MC * 2;
  ushort_t* sr  = (ushort_t*)ws; ws += MC * 2;
  ushort_t* sy  = (ushort_t*)ws; ws += MC * 2;
  float* sa = (float*)ws; ws += (size_t)B_SZ * NCH * C_DIM * 4;
  float* sb = (float*)ws; ws += (size_t)B_SZ * NCH * C_DIM * 4;
  float* sp = (float*)ws; ws += (size_t)B_SZ * NCH * C_DIM * 4;

  prep_kernel<<<dim3(12288), 256, 0, stream>>>(Wk, Wv, Wr, Wo, Wb, x, tm, cm, xmb);

  // fused k/v/r projections: 256x128 tiles, 768 blocks, 3-buf counted vmcnt
  gemm_fused<<<dim3(768), 512, 0, stream>>>(xmb, Wb, kk, vv, sr);

  wkv_phaseA<<<(B_SZ * NCH * C_DIM) / 256, 256, 0, stream>>>(kk, vv, td, sa, sb, sp);
  wkv_phaseC2<<<(B_SZ * NCH * C_DIM) / 256, 256, 0, stream>>>(kk, vv, sr, td, tf, sa, sb, sp, sy);

  // output projection: R6 pipeline, 512 blocks fully resident @ 3/CU
  gemm_out<<<dim3(512), 256, 0, stream>>>(sy, Wb + 3 * CC, (float*)d_out);
}